// Round 5
// baseline (199.899 us; speedup 1.0000x reference)
//
#include <hip/hip_runtime.h>

#define NB 4
#define NQ 128
#define NK 1024
#define NH 256
#define NE 256
#define NV 256

#define TSCALE 2.8853900817779268f  // 2*log2(e)
#define LOG2E  1.4426950408889634f

static __device__ __forceinline__ float fexp2(float x){ return __builtin_amdgcn_exp2f(x); }
static __device__ __forceinline__ float frcp (float x){ return __builtin_amdgcn_rcpf(x); }
static __device__ __forceinline__ float tanh_of(float x){
    float e = fexp2(x * TSCALE);
    return fmaf(-2.0f, frcp(e + 1.0f), 1.0f);
}

// ---------------- proj: blocks [0,128): q-side (4 rows each) -> qdatA/qdatB packed
//                        blocks [128,640): k-side (8 rows each) -> kT4 h-interleaved
// qdatA[(b*32+qq)*256+h] = (Ta_r0, wv*Ta_r0, Ta_r1, wv*Ta_r1); qdatB same for rows 2,3
// kT4[(b*64+hg)*1024+k]  = (Tb[4hg][k], ..., Tb[4hg+3][k])
__global__ __launch_bounds__(256) void proj_kernel(
    const float* __restrict__ qin, const float* __restrict__ kin,
    const float* __restrict__ Wq, const float* __restrict__ Wk,
    const float* __restrict__ Wv,
    float4* __restrict__ qdatA, float4* __restrict__ qdatB,
    float4* __restrict__ kT4) {
    const int tid = threadIdx.x;
    const int bi  = blockIdx.x;
    __shared__ float tr[NH][9];
    if (bi < NB * 32) {
        const int row0 = bi * 4;
        const float* r0 = qin + row0 * NE;
        float a0 = 0.f, a1 = 0.f, a2 = 0.f, a3 = 0.f;
#pragma unroll 2
        for (int e = 0; e < NE; e += 4) {
            float4 q0 = *(const float4*)(r0 + e);
            float4 q1 = *(const float4*)(r0 + NE + e);
            float4 q2 = *(const float4*)(r0 + 2 * NE + e);
            float4 q3 = *(const float4*)(r0 + 3 * NE + e);
#pragma unroll
            for (int j = 0; j < 4; ++j) {
                float w = Wq[(e + j) * NH + tid];
                a0 = fmaf(((const float*)&q0)[j], w, a0);
                a1 = fmaf(((const float*)&q1)[j], w, a1);
                a2 = fmaf(((const float*)&q2)[j], w, a2);
                a3 = fmaf(((const float*)&q3)[j], w, a3);
            }
        }
        float wv = Wv[tid];
        float t0 = tanh_of(a0), t1 = tanh_of(a1), t2 = tanh_of(a2), t3 = tanh_of(a3);
        qdatA[bi * NH + tid] = make_float4(t0, wv * t0, t1, wv * t1);
        qdatB[bi * NH + tid] = make_float4(t2, wv * t2, t3, wv * t3);
    } else {
        const int kb = bi - NB * 32;
        const int b  = kb >> 7;
        const int k0 = (kb & 127) * 8;
        const float* kr = kin + (b * NK + k0) * NE;
        float acc[8] = {0.f,0.f,0.f,0.f,0.f,0.f,0.f,0.f};
#pragma unroll 2
        for (int e = 0; e < NE; e += 4) {
            float4 kvv[8];
#pragma unroll
            for (int i = 0; i < 8; ++i) kvv[i] = *(const float4*)(kr + i * NE + e);
#pragma unroll
            for (int j = 0; j < 4; ++j) {
                float w = Wk[(e + j) * NH + tid];
#pragma unroll
                for (int i = 0; i < 8; ++i)
                    acc[i] = fmaf(((const float*)&kvv[i])[j], w, acc[i]);
            }
        }
#pragma unroll
        for (int i = 0; i < 8; ++i) tr[tid][i] = tanh_of(acc[i]);
        __syncthreads();
#pragma unroll
        for (int p = 0; p < 2; ++p) {
            int idx2 = p * 256 + tid;
            int hg = idx2 >> 3;
            int kk = idx2 & 7;
            float4 v = make_float4(tr[hg*4+0][kk], tr[hg*4+1][kk],
                                   tr[hg*4+2][kk], tr[hg*4+3][kk]);
            kT4[(b * 64 + hg) * NK + k0 + kk] = v;
        }
    }
}

// one h4-step: 4 h-elements x 4 q-rows, ONE rcp via 4-way batched reciprocal
static __device__ __forceinline__ void step4(
    float4 kv4, const float4* __restrict__ qA, const float4* __restrict__ qB,
    const float4* __restrict__ Wv4, int h4,
    float& acc0, float& acc1, float& acc2, float& acc3) {
    float4 wv4 = Wv4[h4];                    // uniform -> scalar cache
#pragma unroll
    for (int j = 0; j < 4; ++j) {
        float kv  = (j==0)?kv4.x:(j==1)?kv4.y:(j==2)?kv4.z:kv4.w;
        float wvj = (j==0)?wv4.x:(j==1)?wv4.y:(j==2)?wv4.z:wv4.w;
        float wvb = wvj * kv;
        float4 qa = qA[h4 * 4 + j];          // uniform -> scalar cache (64B/h4, hot)
        float4 qb = qB[h4 * 4 + j];
        float p0 = fmaf(qa.x, kv, 1.0f), nu0 = qa.y + wvb;
        float p1 = fmaf(qa.z, kv, 1.0f), nu1 = qa.w + wvb;
        float p2 = fmaf(qb.x, kv, 1.0f), nu2 = qb.y + wvb;
        float p3 = fmaf(qb.z, kv, 1.0f), nu3 = qb.w + wvb;
        float ab = p0 * p1, cd = p2 * p3;
        float r  = frcp(ab * cd);
        float rab = r * cd, rcd = r * ab;
        acc0 = fmaf(nu0, rab * p1, acc0);
        acc1 = fmaf(nu1, rab * p0, acc1);
        acc2 = fmaf(nu2, rcd * p3, acc2);
        acc3 = fmaf(nu3, rcd * p2, acc3);
    }
}

// ---------------- fused attention, dense-remapped; kT4 stream explicitly
// register-double-buffered 8 deep so ~8 global_load_dwordx4 stay in flight.
__global__ __launch_bounds__(256) void attn_kernel(
    const float4* __restrict__ qdatA, const float4* __restrict__ qdatB,
    const float4* __restrict__ kT4, const float* __restrict__ V,
    const int* __restrict__ vlen, const float4* __restrict__ Wv4,
    float* __restrict__ part_m, float* __restrict__ part_s,
    float* __restrict__ part_pv) {
    const int tid = threadIdx.x, lane = tid & 63, wid = tid >> 6;
    // dense work remap
    const int n0 = (vlen[0] + 255) >> 8, n1 = (vlen[1] + 255) >> 8;
    const int n2 = (vlen[2] + 255) >> 8, n3 = (vlen[3] + 255) >> 8;
    const int c1 = 32 * n0, c2 = c1 + 32 * n1, c3 = c2 + 32 * n2;
    const int W  = c3 + 32 * n3;
    const int w  = blockIdx.x;
    if (w >= W) return;
    int b, base, nb;
    if      (w >= c3) { b = 3; base = c3; nb = n3; }
    else if (w >= c2) { b = 2; base = c2; nb = n2; }
    else if (w >= c1) { b = 1; base = c1; nb = n1; }
    else              { b = 0; base = 0;  nb = n0; }
    const int rel     = w - base;
    const int qq      = (unsigned)rel / (unsigned)nb;
    const int quarter = rel - qq * nb;
    const int vl      = vlen[b];
    const int pidx = (b * 32 + qq) * 4 + quarter;
    float* pm  = part_m + pidx * 4;
    float* ps  = part_s + pidx * 4;
    float* ppv = part_pv + pidx * (4 * NV);

    __shared__ float  pw[4][NH];
    __shared__ float  pvred[4][64 * 17];
    __shared__ float  red[4][8];

    const float4* qA = qdatA + (b * 32 + qq) * NH;   // wave-uniform
    const float4* qB = qdatB + (b * 32 + qq) * NH;

    const int k = quarter * 256 + tid;
    const float4* kp = kT4 + (b * 64) * NK + k;
    float acc0 = 0.f, acc1 = 0.f, acc2 = 0.f, acc3 = 0.f;

    // explicit register double-buffer, depth 8 (prefetch next batch before compute)
    float4 bufA[8], bufB[8];
#pragma unroll
    for (int i = 0; i < 8; ++i) bufA[i] = kp[i * NK];
#pragma unroll 1
    for (int bp = 0; bp < 4; ++bp) {
        const int h0 = bp * 16;
#pragma unroll
        for (int i = 0; i < 8; ++i) bufB[i] = kp[((h0 + 8 + i) & 63) * NK];
#pragma unroll
        for (int i = 0; i < 8; ++i)
            step4(bufA[i], qA, qB, Wv4, h0 + i, acc0, acc1, acc2, acc3);
#pragma unroll
        for (int i = 0; i < 8; ++i) bufA[i] = kp[((h0 + 16 + i) & 63) * NK];  // wrap: harmless L2-hot read
#pragma unroll
        for (int i = 0; i < 8; ++i)
            step4(bufB[i], qA, qB, Wv4, h0 + 8 + i, acc0, acc1, acc2, acc3);
    }

    const bool okk = k < vl;
    float s0 = okk ? acc0 : -1e30f;
    float s1 = okk ? acc1 : -1e30f;
    float s2 = okk ? acc2 : -1e30f;
    float s3 = okk ? acc3 : -1e30f;
    float m0 = s0, m1 = s1, m2 = s2, m3 = s3;
#pragma unroll
    for (int d = 32; d >= 1; d >>= 1) {
        m0 = fmaxf(m0, __shfl_xor(m0, d, 64));
        m1 = fmaxf(m1, __shfl_xor(m1, d, 64));
        m2 = fmaxf(m2, __shfl_xor(m2, d, 64));
        m3 = fmaxf(m3, __shfl_xor(m3, d, 64));
    }
    if (lane == 0) { red[wid][0]=m0; red[wid][1]=m1; red[wid][2]=m2; red[wid][3]=m3; }
    __syncthreads();
    m0 = fmaxf(fmaxf(red[0][0], red[1][0]), fmaxf(red[2][0], red[3][0]));
    m1 = fmaxf(fmaxf(red[0][1], red[1][1]), fmaxf(red[2][1], red[3][1]));
    m2 = fmaxf(fmaxf(red[0][2], red[1][2]), fmaxf(red[2][2], red[3][2]));
    m3 = fmaxf(fmaxf(red[0][3], red[1][3]), fmaxf(red[2][3], red[3][3]));
    float p0 = fexp2((s0 - m0) * LOG2E);
    float p1 = fexp2((s1 - m1) * LOG2E);
    float p2 = fexp2((s2 - m2) * LOG2E);
    float p3 = fexp2((s3 - m3) * LOG2E);
    pw[0][tid] = p0; pw[1][tid] = p1; pw[2][tid] = p2; pw[3][tid] = p3;
    float u0 = p0, u1 = p1, u2 = p2, u3 = p3;
#pragma unroll
    for (int d = 32; d >= 1; d >>= 1) {
        u0 += __shfl_xor(u0, d, 64); u1 += __shfl_xor(u1, d, 64);
        u2 += __shfl_xor(u2, d, 64); u3 += __shfl_xor(u3, d, 64);
    }
    if (lane == 0) { red[wid][4]=u0; red[wid][5]=u1; red[wid][6]=u2; red[wid][7]=u3; }
    __syncthreads();
    if (tid == 0) {
        pm[0] = m0; pm[1] = m1; pm[2] = m2; pm[3] = m3;
        ps[0] = red[0][4]+red[1][4]+red[2][4]+red[3][4];
        ps[1] = red[0][5]+red[1][5]+red[2][5]+red[3][5];
        ps[2] = red[0][6]+red[1][6]+red[2][6]+red[3][6];
        ps[3] = red[0][7]+red[1][7]+red[2][7]+red[3][7];
    }
    // PV over this chunk
    const float* Vb = V + (b * NK + quarter * 256) * NV;
    const int v4 = lane * 4;
    float4 o0 = {0,0,0,0}, o1 = {0,0,0,0}, o2 = {0,0,0,0}, o3 = {0,0,0,0};
    for (int kk0 = wid * 4; kk0 < 256; kk0 += 16) {
        float4 pr0 = *(const float4*)&pw[0][kk0];
        float4 pr1 = *(const float4*)&pw[1][kk0];
        float4 pr2 = *(const float4*)&pw[2][kk0];
        float4 pr3 = *(const float4*)&pw[3][kk0];
#pragma unroll
        for (int j = 0; j < 4; ++j) {
            float4 vv = *(const float4*)&Vb[(kk0 + j) * NV + v4];
            float w0 = ((const float*)&pr0)[j], w1 = ((const float*)&pr1)[j];
            float w2 = ((const float*)&pr2)[j], w3 = ((const float*)&pr3)[j];
            o0.x = fmaf(w0, vv.x, o0.x); o0.y = fmaf(w0, vv.y, o0.y);
            o0.z = fmaf(w0, vv.z, o0.z); o0.w = fmaf(w0, vv.w, o0.w);
            o1.x = fmaf(w1, vv.x, o1.x); o1.y = fmaf(w1, vv.y, o1.y);
            o1.z = fmaf(w1, vv.z, o1.z); o1.w = fmaf(w1, vv.w, o1.w);
            o2.x = fmaf(w2, vv.x, o2.x); o2.y = fmaf(w2, vv.y, o2.y);
            o2.z = fmaf(w2, vv.z, o2.z); o2.w = fmaf(w2, vv.w, o2.w);
            o3.x = fmaf(w3, vv.x, o3.x); o3.y = fmaf(w3, vv.y, o3.y);
            o3.z = fmaf(w3, vv.z, o3.z); o3.w = fmaf(w3, vv.w, o3.w);
        }
    }
    {
        float* pd = &pvred[wid][lane * 17];
        *(float4*)(pd + 0)  = o0;
        *(float4*)(pd + 4)  = o1;
        *(float4*)(pd + 8)  = o2;
        *(float4*)(pd + 12) = o3;
    }
    __syncthreads();
    {
        int row = tid >> 6, vg = tid & 63;
        float4 r = {0,0,0,0};
#pragma unroll
        for (int ww = 0; ww < 4; ++ww) {
            float4 t = *(const float4*)&pvred[ww][vg * 17 + row * 4];
            r.x += t.x; r.y += t.y; r.z += t.z; r.w += t.w;
        }
        *(float4*)&ppv[row * NV + vg * 4] = r;
    }
}

// ---------------- combine: merge the VALID chunk partials per (b,qq)
__global__ __launch_bounds__(256) void combine_kernel(
    const float* __restrict__ part_m, const float* __restrict__ part_s,
    const float* __restrict__ part_pv, const int* __restrict__ vlen,
    float* __restrict__ out) {
    const int tid = threadIdx.x;
    const int bi  = blockIdx.x;   // 0..127 = b*32+qq
    const int b   = bi >> 5;
    const int nb  = (vlen[b] + 255) >> 8;   // valid quarters
    const int base = bi * 4;
#pragma unroll
    for (int i = 0; i < 4; ++i) {
        float m[4], s[4];
        for (int q = 0; q < nb; ++q) {
            m[q] = part_m[(base + q) * 4 + i];
            s[q] = part_s[(base + q) * 4 + i];
        }
        float M = m[0];
        for (int q = 1; q < nb; ++q) M = fmaxf(M, m[q]);
        float wq[4], S = 0.f;
        for (int q = 0; q < nb; ++q) {
            wq[q] = fexp2((m[q] - M) * LOG2E);
            S = fmaf(s[q], wq[q], S);
        }
        float o = 0.f;
        for (int q = 0; q < nb; ++q)
            o = fmaf(part_pv[((base + q) * 4 + i) * NV + tid], wq[q], o);
        out[(base + i) * NV + tid] = o * frcp(S);
    }
}

extern "C" void kernel_launch(void* const* d_in, const int* in_sizes, int n_in,
                              void* d_out, int out_size, void* d_ws, size_t ws_size,
                              hipStream_t stream) {
    const float* queries = (const float*)d_in[0];
    const float* keys    = (const float*)d_in[1];
    const float* values  = (const float*)d_in[2];
    const int*   vlens   = (const int*)  d_in[3];
    const float* Wq      = (const float*)d_in[4];
    const float* Wk      = (const float*)d_in[5];
    const float* Wv      = (const float*)d_in[6];
    float* out = (float*)d_out;

    float4* qdatA  = (float4*)d_ws;                  // 32768 float4 (512 KB)
    float4* qdatB  = qdatA + NB * 32 * NH;           // 32768 float4 (512 KB)
    float4* kT4    = qdatB + NB * 32 * NH;           // 262144 float4 (4 MB)
    float*  part_m = (float*)(kT4 + NB * 64 * NK);   // 2048 floats
    float*  part_s = part_m + 2048;                  // 2048 floats
    float*  part_pv = part_s + 2048;                 // 524288 floats (2 MB)

    proj_kernel   <<<dim3(640), dim3(256), 0, stream>>>(queries, keys, Wq, Wk, Wv,
                                                        qdatA, qdatB, kT4);
    attn_kernel   <<<dim3(512), dim3(256), 0, stream>>>(qdatA, qdatB, kT4, values,
                                                        vlens, (const float4*)Wv,
                                                        part_m, part_s, part_pv);
    combine_kernel<<<dim3(128), dim3(256), 0, stream>>>(part_m, part_s, part_pv,
                                                        vlens, out);
}

// Round 6
// 135.773 us; speedup vs baseline: 1.4723x; 1.4723x over previous
//
#include <hip/hip_runtime.h>

#define NB 4
#define NQ 128
#define NK 1024
#define NH 256
#define NE 256
#define NV 256

#define TSCALE 2.8853900817779268f  // 2*log2(e)
#define LOG2E  1.4426950408889634f

static __device__ __forceinline__ float fexp2(float x){ return __builtin_amdgcn_exp2f(x); }
static __device__ __forceinline__ float frcp (float x){ return __builtin_amdgcn_rcpf(x); }
static __device__ __forceinline__ float tanh_of(float x){
    float e = fexp2(x * TSCALE);
    return fmaf(-2.0f, frcp(e + 1.0f), 1.0f);
}

// ---------------- proj: blocks [0,128): q-side (4 rows each) -> qdatA/qdatB packed
//                        blocks [128,640): k-side (8 rows each) -> kT4 h-interleaved
// qdatA[(b*32+qq)*256+h] = (Ta_r0, wv*Ta_r0, Ta_r1, wv*Ta_r1); qdatB same for rows 2,3
// kT4[(b*64+hg)*1024+k]  = (Tb[4hg][k], ..., Tb[4hg+3][k])
__global__ __launch_bounds__(256) void proj_kernel(
    const float* __restrict__ qin, const float* __restrict__ kin,
    const float* __restrict__ Wq, const float* __restrict__ Wk,
    const float* __restrict__ Wv,
    float4* __restrict__ qdatA, float4* __restrict__ qdatB,
    float4* __restrict__ kT4) {
    const int tid = threadIdx.x;
    const int bi  = blockIdx.x;
    __shared__ float tr[NH][9];
    if (bi < NB * 32) {
        const int row0 = bi * 4;
        const float* r0 = qin + row0 * NE;
        float a0 = 0.f, a1 = 0.f, a2 = 0.f, a3 = 0.f;
#pragma unroll 2
        for (int e = 0; e < NE; e += 4) {
            float4 q0 = *(const float4*)(r0 + e);
            float4 q1 = *(const float4*)(r0 + NE + e);
            float4 q2 = *(const float4*)(r0 + 2 * NE + e);
            float4 q3 = *(const float4*)(r0 + 3 * NE + e);
#pragma unroll
            for (int j = 0; j < 4; ++j) {
                float w = Wq[(e + j) * NH + tid];
                a0 = fmaf(((const float*)&q0)[j], w, a0);
                a1 = fmaf(((const float*)&q1)[j], w, a1);
                a2 = fmaf(((const float*)&q2)[j], w, a2);
                a3 = fmaf(((const float*)&q3)[j], w, a3);
            }
        }
        float wv = Wv[tid];
        float t0 = tanh_of(a0), t1 = tanh_of(a1), t2 = tanh_of(a2), t3 = tanh_of(a3);
        qdatA[bi * NH + tid] = make_float4(t0, wv * t0, t1, wv * t1);
        qdatB[bi * NH + tid] = make_float4(t2, wv * t2, t3, wv * t3);
    } else {
        const int kb = bi - NB * 32;
        const int b  = kb >> 7;
        const int k0 = (kb & 127) * 8;
        const float* kr = kin + (b * NK + k0) * NE;
        float acc[8] = {0.f,0.f,0.f,0.f,0.f,0.f,0.f,0.f};
#pragma unroll 2
        for (int e = 0; e < NE; e += 4) {
            float4 kvv[8];
#pragma unroll
            for (int i = 0; i < 8; ++i) kvv[i] = *(const float4*)(kr + i * NE + e);
#pragma unroll
            for (int j = 0; j < 4; ++j) {
                float w = Wk[(e + j) * NH + tid];
#pragma unroll
                for (int i = 0; i < 8; ++i)
                    acc[i] = fmaf(((const float*)&kvv[i])[j], w, acc[i]);
            }
        }
#pragma unroll
        for (int i = 0; i < 8; ++i) tr[tid][i] = tanh_of(acc[i]);
        __syncthreads();
#pragma unroll
        for (int p = 0; p < 2; ++p) {
            int idx2 = p * 256 + tid;
            int hg = idx2 >> 3;
            int kk = idx2 & 7;
            float4 v = make_float4(tr[hg*4+0][kk], tr[hg*4+1][kk],
                                   tr[hg*4+2][kk], tr[hg*4+3][kk]);
            kT4[(b * 64 + hg) * NK + k0 + kk] = v;
        }
    }
}

// one h4-step: 4 h-elements x 4 q-rows, ONE rcp via 4-way batched reciprocal
static __device__ __forceinline__ void step4(
    float4 kv4, const float4* __restrict__ qA, const float4* __restrict__ qB,
    const float4* __restrict__ Wv4, int h4,
    float& acc0, float& acc1, float& acc2, float& acc3) {
    float4 wv4 = Wv4[h4];                    // wave-uniform -> scalar cache
#pragma unroll
    for (int j = 0; j < 4; ++j) {
        float kv  = (j==0)?kv4.x:(j==1)?kv4.y:(j==2)?kv4.z:kv4.w;
        float wvj = (j==0)?wv4.x:(j==1)?wv4.y:(j==2)?wv4.z:wv4.w;
        float wvb = wvj * kv;
        float4 qa = qA[h4 * 4 + j];          // wave-uniform -> scalar cache
        float4 qb = qB[h4 * 4 + j];
        float p0 = fmaf(qa.x, kv, 1.0f), nu0 = qa.y + wvb;
        float p1 = fmaf(qa.z, kv, 1.0f), nu1 = qa.w + wvb;
        float p2 = fmaf(qb.x, kv, 1.0f), nu2 = qb.y + wvb;
        float p3 = fmaf(qb.z, kv, 1.0f), nu3 = qb.w + wvb;
        float ab = p0 * p1, cd = p2 * p3;
        float r  = frcp(ab * cd);
        float rab = r * cd, rcd = r * ab;
        acc0 = fmaf(nu0, rab * p1, acc0);
        acc1 = fmaf(nu1, rab * p0, acc1);
        acc2 = fmaf(nu2, rcd * p3, acc2);
        acc3 = fmaf(nu3, rcd * p2, acc3);
    }
}

// ---------------- fused attention, TLP-repartitioned:
// block = (b, qq, 64-wide k-chunk); wave w owns h-quarter [64w,64w+64);
// LDS cross-wave h-reduce, per-wave softmax (wave = q-row), split PV.
// Dense remap over valid chunks (nb = ceil(vl/64) per batch), grid 2048.
__global__ __launch_bounds__(256) void attn_kernel(
    const float4* __restrict__ qdatA, const float4* __restrict__ qdatB,
    const float4* __restrict__ kT4, const float* __restrict__ V,
    const int* __restrict__ vlen, const float4* __restrict__ Wv4,
    float* __restrict__ part_m, float* __restrict__ part_s,
    float* __restrict__ part_pv) {
    const int tid = threadIdx.x, lane = tid & 63, wvid = tid >> 6;
    // dense work remap (chunk = 64 k)
    const int n0 = (vlen[0] + 63) >> 6, n1 = (vlen[1] + 63) >> 6;
    const int n2 = (vlen[2] + 63) >> 6, n3 = (vlen[3] + 63) >> 6;
    const int c1 = 32 * n0, c2 = c1 + 32 * n1, c3 = c2 + 32 * n2;
    const int W  = c3 + 32 * n3;
    const int w  = blockIdx.x;
    if (w >= W) return;
    int b, base, nb;
    if      (w >= c3) { b = 3; base = c3; nb = n3; }
    else if (w >= c2) { b = 2; base = c2; nb = n2; }
    else if (w >= c1) { b = 1; base = c1; nb = n1; }
    else              { b = 0; base = 0;  nb = n0; }
    const int rel   = w - base;
    const int qq    = (unsigned)rel / (unsigned)nb;
    const int chunk = rel - qq * nb;
    const int vl    = vlen[b];
    const int k0    = chunk * 64;
    const int k     = k0 + lane;
    const int pidx  = (b * 32 + qq) * 16 + chunk;
    float* pm  = part_m + pidx * 4;
    float* ps  = part_s + pidx * 4;
    float* ppv = part_pv + pidx * (4 * NV);

    __shared__ float red17[4][64 * 17];   // phase A: h-partials; phase B: pv-partials
    __shared__ float pwS[4][64];          // softmax weights, [q-row][k-lane]

    const float4* qA = qdatA + (b * 32 + qq) * NH;   // wave-uniform
    const float4* qB = qdatB + (b * 32 + qq) * NH;

    // phase A: scores — wave wvid covers h4 in [wvid*16, wvid*16+16)
    const float4* kp = kT4 + (b * 64 + wvid * 16) * NK + k;
    float acc0 = 0.f, acc1 = 0.f, acc2 = 0.f, acc3 = 0.f;
#pragma unroll 4
    for (int i = 0; i < 16; ++i) {
        float4 kv4 = kp[i * NK];          // coalesced dwordx4, L2-resident
        step4(kv4, qA, qB, Wv4, wvid * 16 + i, acc0, acc1, acc2, acc3);
    }
    {
        float* hp = &red17[wvid][lane * 17];
        hp[0] = acc0; hp[1] = acc1; hp[2] = acc2; hp[3] = acc3;
    }
    __syncthreads();
    // cross-wave h-reduce; wave = q-row, lane = k-lane
    {
        const int row = wvid;
        float s = red17[0][lane * 17 + row] + red17[1][lane * 17 + row]
                + red17[2][lane * 17 + row] + red17[3][lane * 17 + row];
        s = (k < vl) ? s : -1e30f;
        float m = s;
#pragma unroll
        for (int d = 32; d >= 1; d >>= 1) m = fmaxf(m, __shfl_xor(m, d, 64));
        float p = fexp2((s - m) * LOG2E);     // masked -> exactly 0
        float u = p;
#pragma unroll
        for (int d = 32; d >= 1; d >>= 1) u += __shfl_xor(u, d, 64);
        if (lane == 0) { pm[row] = m; ps[row] = u; }
        pwS[row][lane] = p;
    }
    __syncthreads();
    // phase B: PV — wave wvid covers kk in [wvid*16, wvid*16+16), all 4 q-rows
    {
        const float* Vb = V + (b * NK + k0) * NV;
        const int v4 = lane * 4;
        float4 o0 = {0,0,0,0}, o1 = {0,0,0,0}, o2 = {0,0,0,0}, o3 = {0,0,0,0};
#pragma unroll 4
        for (int kk = 0; kk < 16; ++kk) {
            const int kkk = wvid * 16 + kk;
            float p0 = pwS[0][kkk], p1 = pwS[1][kkk];   // uniform addr -> broadcast
            float p2 = pwS[2][kkk], p3 = pwS[3][kkk];
            float4 vv = *(const float4*)&Vb[kkk * NV + v4];
            o0.x = fmaf(p0, vv.x, o0.x); o0.y = fmaf(p0, vv.y, o0.y);
            o0.z = fmaf(p0, vv.z, o0.z); o0.w = fmaf(p0, vv.w, o0.w);
            o1.x = fmaf(p1, vv.x, o1.x); o1.y = fmaf(p1, vv.y, o1.y);
            o1.z = fmaf(p1, vv.z, o1.z); o1.w = fmaf(p1, vv.w, o1.w);
            o2.x = fmaf(p2, vv.x, o2.x); o2.y = fmaf(p2, vv.y, o2.y);
            o2.z = fmaf(p2, vv.z, o2.z); o2.w = fmaf(p2, vv.w, o2.w);
            o3.x = fmaf(p3, vv.x, o3.x); o3.y = fmaf(p3, vv.y, o3.y);
            o3.z = fmaf(p3, vv.z, o3.z); o3.w = fmaf(p3, vv.w, o3.w);
        }
        float* pd = &red17[wvid][lane * 17];
        *(float4*)(pd + 0)  = o0;
        *(float4*)(pd + 4)  = o1;
        *(float4*)(pd + 8)  = o2;
        *(float4*)(pd + 12) = o3;
    }
    __syncthreads();
    {
        const int row = tid >> 6, vg = tid & 63;
        float4 r = {0,0,0,0};
#pragma unroll
        for (int ww = 0; ww < 4; ++ww) {
            float4 t = *(const float4*)&red17[ww][vg * 17 + row * 4];
            r.x += t.x; r.y += t.y; r.z += t.z; r.w += t.w;
        }
        *(float4*)&ppv[row * NV + vg * 4] = r;
    }
}

// ---------------- combine: merge the VALID (<=16) chunk partials per (b,qq)
__global__ __launch_bounds__(256) void combine_kernel(
    const float* __restrict__ part_m, const float* __restrict__ part_s,
    const float* __restrict__ part_pv, const int* __restrict__ vlen,
    float* __restrict__ out) {
    const int tid = threadIdx.x;
    const int bi  = blockIdx.x;   // 0..127 = b*32+qq
    const int b   = bi >> 5;
    const int nb  = (vlen[b] + 63) >> 6;    // valid chunks (1..16)
    const int base = bi * 16;
#pragma unroll
    for (int i = 0; i < 4; ++i) {
        float M = -1e30f;
        for (int q = 0; q < nb; ++q)
            M = fmaxf(M, part_m[(base + q) * 4 + i]);
        float S = 0.f, o = 0.f;
        for (int q = 0; q < nb; ++q) {
            float wq = fexp2((part_m[(base + q) * 4 + i] - M) * LOG2E);
            S = fmaf(part_s[(base + q) * 4 + i], wq, S);
            o = fmaf(part_pv[((base + q) * 4 + i) * NV + tid], wq, o);
        }
        out[(bi * 4 + i) * NV + tid] = o * frcp(S);
    }
}

extern "C" void kernel_launch(void* const* d_in, const int* in_sizes, int n_in,
                              void* d_out, int out_size, void* d_ws, size_t ws_size,
                              hipStream_t stream) {
    const float* queries = (const float*)d_in[0];
    const float* keys    = (const float*)d_in[1];
    const float* values  = (const float*)d_in[2];
    const int*   vlens   = (const int*)  d_in[3];
    const float* Wq      = (const float*)d_in[4];
    const float* Wk      = (const float*)d_in[5];
    const float* Wv      = (const float*)d_in[6];
    float* out = (float*)d_out;

    float4* qdatA  = (float4*)d_ws;                  // 32768 float4 (512 KB)
    float4* qdatB  = qdatA + NB * 32 * NH;           // 32768 float4 (512 KB)
    float4* kT4    = qdatB + NB * 32 * NH;           // 262144 float4 (4 MB)
    float*  part_m = (float*)(kT4 + NB * 64 * NK);   // 8192 floats
    float*  part_s = part_m + 8192;                  // 8192 floats
    float*  part_pv = part_s + 8192;                 // 2M floats (8 MB)

    proj_kernel   <<<dim3(640), dim3(256), 0, stream>>>(queries, keys, Wq, Wk, Wv,
                                                        qdatA, qdatB, kT4);
    attn_kernel   <<<dim3(2048), dim3(256), 0, stream>>>(qdatA, qdatB, kT4, values,
                                                         vlens, (const float4*)Wv,
                                                         part_m, part_s, part_pv);
    combine_kernel<<<dim3(128), dim3(256), 0, stream>>>(part_m, part_s, part_pv,
                                                        vlens, out);
}

// Round 7
// 126.125 us; speedup vs baseline: 1.5849x; 1.0765x over previous
//
#include <hip/hip_runtime.h>

#define NB 4
#define NQ 128
#define NK 1024
#define NH 256
#define NE 256
#define NV 256

#define TSCALE 2.8853900817779268f  // 2*log2(e)
#define LOG2E  1.4426950408889634f

static __device__ __forceinline__ float fexp2(float x){ return __builtin_amdgcn_exp2f(x); }
static __device__ __forceinline__ float frcp (float x){ return __builtin_amdgcn_rcpf(x); }
static __device__ __forceinline__ float tanh_of(float x){
    float e = fexp2(x * TSCALE);
    return fmaf(-2.0f, frcp(e + 1.0f), 1.0f);
}

// ---------------- proj: blocks [0,128): q-side (4 rows each) -> qdatA/qdatB packed
//                        blocks [128,640): k-side (8 rows each) -> kTt tiled
// qdatA[(b*32+qq)*256+h] = (Ta_r0, wv*Ta_r0, Ta_r1, wv*Ta_r1); qdatB rows 2,3
// kTt float4 index: ((b*16 + c)*64 + h4)*64 + kl   (c = k>>6, kl = k&63)
//   -> each (b,chunk) tile is 64KB contiguous; a wave's h-quarter is a
//      contiguous 16KB window (sequential 1KB loads, no 16KB stride).
__global__ __launch_bounds__(256) void proj_kernel(
    const float* __restrict__ qin, const float* __restrict__ kin,
    const float* __restrict__ Wq, const float* __restrict__ Wk,
    const float* __restrict__ Wv,
    float4* __restrict__ qdatA, float4* __restrict__ qdatB,
    float4* __restrict__ kTt) {
    const int tid = threadIdx.x;
    const int bi  = blockIdx.x;
    __shared__ float tr[NH][9];
    if (bi < NB * 32) {
        const int row0 = bi * 4;
        const float* r0 = qin + row0 * NE;
        float a0 = 0.f, a1 = 0.f, a2 = 0.f, a3 = 0.f;
#pragma unroll 2
        for (int e = 0; e < NE; e += 4) {
            float4 q0 = *(const float4*)(r0 + e);
            float4 q1 = *(const float4*)(r0 + NE + e);
            float4 q2 = *(const float4*)(r0 + 2 * NE + e);
            float4 q3 = *(const float4*)(r0 + 3 * NE + e);
#pragma unroll
            for (int j = 0; j < 4; ++j) {
                float w = Wq[(e + j) * NH + tid];
                a0 = fmaf(((const float*)&q0)[j], w, a0);
                a1 = fmaf(((const float*)&q1)[j], w, a1);
                a2 = fmaf(((const float*)&q2)[j], w, a2);
                a3 = fmaf(((const float*)&q3)[j], w, a3);
            }
        }
        float wv = Wv[tid];
        float t0 = tanh_of(a0), t1 = tanh_of(a1), t2 = tanh_of(a2), t3 = tanh_of(a3);
        qdatA[bi * NH + tid] = make_float4(t0, wv * t0, t1, wv * t1);
        qdatB[bi * NH + tid] = make_float4(t2, wv * t2, t3, wv * t3);
    } else {
        const int kb = bi - NB * 32;
        const int b  = kb >> 7;
        const int k0 = (kb & 127) * 8;
        const int c   = k0 >> 6;          // 64-k chunk
        const int kl0 = k0 & 63;          // lane offset inside chunk
        const float* kr = kin + (b * NK + k0) * NE;
        float acc[8] = {0.f,0.f,0.f,0.f,0.f,0.f,0.f,0.f};
#pragma unroll 2
        for (int e = 0; e < NE; e += 4) {
            float4 kvv[8];
#pragma unroll
            for (int i = 0; i < 8; ++i) kvv[i] = *(const float4*)(kr + i * NE + e);
#pragma unroll
            for (int j = 0; j < 4; ++j) {
                float w = Wk[(e + j) * NH + tid];
#pragma unroll
                for (int i = 0; i < 8; ++i)
                    acc[i] = fmaf(((const float*)&kvv[i])[j], w, acc[i]);
            }
        }
#pragma unroll
        for (int i = 0; i < 8; ++i) tr[tid][i] = tanh_of(acc[i]);
        __syncthreads();
#pragma unroll
        for (int p = 0; p < 2; ++p) {
            int idx2 = p * 256 + tid;
            int hg = idx2 >> 3;           // h4 row 0..63
            int kk = idx2 & 7;
            float4 v = make_float4(tr[hg*4+0][kk], tr[hg*4+1][kk],
                                   tr[hg*4+2][kk], tr[hg*4+3][kk]);
            kTt[((b * 16 + c) * 64 + hg) * 64 + kl0 + kk] = v;
        }
    }
}

// one h4-step: 4 h-elements x 4 q-rows, ONE rcp via 4-way batched reciprocal
static __device__ __forceinline__ void step4(
    float4 kv4, const float4* __restrict__ qA, const float4* __restrict__ qB,
    const float4* __restrict__ Wv4, int h4,
    float& acc0, float& acc1, float& acc2, float& acc3) {
    float4 wv4 = Wv4[h4];                    // wave-uniform -> scalar cache
#pragma unroll
    for (int j = 0; j < 4; ++j) {
        float kv  = (j==0)?kv4.x:(j==1)?kv4.y:(j==2)?kv4.z:kv4.w;
        float wvj = (j==0)?wv4.x:(j==1)?wv4.y:(j==2)?wv4.z:wv4.w;
        float wvb = wvj * kv;
        float4 qa = qA[h4 * 4 + j];          // wave-uniform -> scalar cache
        float4 qb = qB[h4 * 4 + j];
        float p0 = fmaf(qa.x, kv, 1.0f), nu0 = qa.y + wvb;
        float p1 = fmaf(qa.z, kv, 1.0f), nu1 = qa.w + wvb;
        float p2 = fmaf(qb.x, kv, 1.0f), nu2 = qb.y + wvb;
        float p3 = fmaf(qb.z, kv, 1.0f), nu3 = qb.w + wvb;
        float ab = p0 * p1, cd = p2 * p3;
        float r  = frcp(ab * cd);
        float rab = r * cd, rcd = r * ab;
        acc0 = fmaf(nu0, rab * p1, acc0);
        acc1 = fmaf(nu1, rab * p0, acc1);
        acc2 = fmaf(nu2, rcd * p3, acc2);
        acc3 = fmaf(nu3, rcd * p2, acc3);
    }
}

// ---------------- fused attention: block = (b, qq, 64-wide k-chunk);
// wave w owns h-quarter [64w,64w+64) — now a CONTIGUOUS 16KB window of kTt.
__global__ __launch_bounds__(256) void attn_kernel(
    const float4* __restrict__ qdatA, const float4* __restrict__ qdatB,
    const float4* __restrict__ kTt, const float* __restrict__ V,
    const int* __restrict__ vlen, const float4* __restrict__ Wv4,
    float* __restrict__ part_m, float* __restrict__ part_s,
    float* __restrict__ part_pv) {
    const int tid = threadIdx.x, lane = tid & 63, wvid = tid >> 6;
    // dense work remap (chunk = 64 k)
    const int n0 = (vlen[0] + 63) >> 6, n1 = (vlen[1] + 63) >> 6;
    const int n2 = (vlen[2] + 63) >> 6, n3 = (vlen[3] + 63) >> 6;
    const int c1 = 32 * n0, c2 = c1 + 32 * n1, c3 = c2 + 32 * n2;
    const int W  = c3 + 32 * n3;
    const int w  = blockIdx.x;
    if (w >= W) return;
    int b, base, nb;
    if      (w >= c3) { b = 3; base = c3; nb = n3; }
    else if (w >= c2) { b = 2; base = c2; nb = n2; }
    else if (w >= c1) { b = 1; base = c1; nb = n1; }
    else              { b = 0; base = 0;  nb = n0; }
    const int rel   = w - base;
    const int qq    = (unsigned)rel / (unsigned)nb;
    const int chunk = rel - qq * nb;
    const int vl    = vlen[b];
    const int k0    = chunk * 64;
    const int k     = k0 + lane;
    const int pidx  = (b * 32 + qq) * 16 + chunk;
    float* pm  = part_m + pidx * 4;
    float* ps  = part_s + pidx * 4;
    float* ppv = part_pv + pidx * (4 * NV);

    __shared__ float red17[4][64 * 17];   // phase A: h-partials; phase B: pv-partials
    __shared__ float pwS[4][64];          // softmax weights, [q-row][k-lane]

    const float4* qA = qdatA + (b * 32 + qq) * NH;   // wave-uniform
    const float4* qB = qdatB + (b * 32 + qq) * NH;

    // phase A: scores — wave wvid reads contiguous 16KB: kTt tile (b,chunk),
    // rows h4 = wvid*16 .. +16, lane-th float4 of each 1KB row.
    const float4* kp = kTt + ((b * 16 + chunk) * 64 + wvid * 16) * 64 + lane;
    float acc0 = 0.f, acc1 = 0.f, acc2 = 0.f, acc3 = 0.f;
#pragma unroll 4
    for (int i = 0; i < 16; ++i) {
        float4 kv4 = kp[i * 64];          // sequential 1KB wave-loads
        step4(kv4, qA, qB, Wv4, wvid * 16 + i, acc0, acc1, acc2, acc3);
    }
    {
        float* hp = &red17[wvid][lane * 17];
        hp[0] = acc0; hp[1] = acc1; hp[2] = acc2; hp[3] = acc3;
    }
    __syncthreads();
    // cross-wave h-reduce; wave = q-row, lane = k-lane
    {
        const int row = wvid;
        float s = red17[0][lane * 17 + row] + red17[1][lane * 17 + row]
                + red17[2][lane * 17 + row] + red17[3][lane * 17 + row];
        s = (k < vl) ? s : -1e30f;
        float m = s;
#pragma unroll
        for (int d = 32; d >= 1; d >>= 1) m = fmaxf(m, __shfl_xor(m, d, 64));
        float p = fexp2((s - m) * LOG2E);     // masked -> exactly 0
        float u = p;
#pragma unroll
        for (int d = 32; d >= 1; d >>= 1) u += __shfl_xor(u, d, 64);
        if (lane == 0) { pm[row] = m; ps[row] = u; }
        pwS[row][lane] = p;
    }
    __syncthreads();
    // phase B: PV — wave wvid covers kk in [wvid*16, wvid*16+16), all 4 q-rows
    {
        const float* Vb = V + (b * NK + k0) * NV;
        const int v4 = lane * 4;
        float4 o0 = {0,0,0,0}, o1 = {0,0,0,0}, o2 = {0,0,0,0}, o3 = {0,0,0,0};
#pragma unroll 4
        for (int kk = 0; kk < 16; ++kk) {
            const int kkk = wvid * 16 + kk;
            float p0 = pwS[0][kkk], p1 = pwS[1][kkk];   // uniform -> broadcast
            float p2 = pwS[2][kkk], p3 = pwS[3][kkk];
            float4 vv = *(const float4*)&Vb[kkk * NV + v4];
            o0.x = fmaf(p0, vv.x, o0.x); o0.y = fmaf(p0, vv.y, o0.y);
            o0.z = fmaf(p0, vv.z, o0.z); o0.w = fmaf(p0, vv.w, o0.w);
            o1.x = fmaf(p1, vv.x, o1.x); o1.y = fmaf(p1, vv.y, o1.y);
            o1.z = fmaf(p1, vv.z, o1.z); o1.w = fmaf(p1, vv.w, o1.w);
            o2.x = fmaf(p2, vv.x, o2.x); o2.y = fmaf(p2, vv.y, o2.y);
            o2.z = fmaf(p2, vv.z, o2.z); o2.w = fmaf(p2, vv.w, o2.w);
            o3.x = fmaf(p3, vv.x, o3.x); o3.y = fmaf(p3, vv.y, o3.y);
            o3.z = fmaf(p3, vv.z, o3.z); o3.w = fmaf(p3, vv.w, o3.w);
        }
        float* pd = &red17[wvid][lane * 17];
        *(float4*)(pd + 0)  = o0;
        *(float4*)(pd + 4)  = o1;
        *(float4*)(pd + 8)  = o2;
        *(float4*)(pd + 12) = o3;
    }
    __syncthreads();
    {
        const int row = tid >> 6, vg = tid & 63;
        float4 r = {0,0,0,0};
#pragma unroll
        for (int ww = 0; ww < 4; ++ww) {
            float4 t = *(const float4*)&red17[ww][vg * 17 + row * 4];
            r.x += t.x; r.y += t.y; r.z += t.z; r.w += t.w;
        }
        *(float4*)&ppv[row * NV + vg * 4] = r;
    }
}

// ---------------- combine: 512 blocks — one (b*32+qq, q-row) each
__global__ __launch_bounds__(256) void combine_kernel(
    const float* __restrict__ part_m, const float* __restrict__ part_s,
    const float* __restrict__ part_pv, const int* __restrict__ vlen,
    float* __restrict__ out) {
    const int tid = threadIdx.x;
    const int idx = blockIdx.x;     // 0..511
    const int bi  = idx >> 2;       // b*32+qq
    const int i   = idx & 3;        // q-row within group
    const int b   = bi >> 5;
    const int nb  = (vlen[b] + 63) >> 6;    // valid chunks (1..16)
    const int base = bi * 16;
    float M = -1e30f;
    for (int q = 0; q < nb; ++q)
        M = fmaxf(M, part_m[(base + q) * 4 + i]);
    float S = 0.f, o = 0.f;
    for (int q = 0; q < nb; ++q) {
        float wq = fexp2((part_m[(base + q) * 4 + i] - M) * LOG2E);
        S = fmaf(part_s[(base + q) * 4 + i], wq, S);
        o = fmaf(part_pv[((base + q) * 4 + i) * NV + tid], wq, o);
    }
    out[(bi * 4 + i) * NV + tid] = o * frcp(S);
}

extern "C" void kernel_launch(void* const* d_in, const int* in_sizes, int n_in,
                              void* d_out, int out_size, void* d_ws, size_t ws_size,
                              hipStream_t stream) {
    const float* queries = (const float*)d_in[0];
    const float* keys    = (const float*)d_in[1];
    const float* values  = (const float*)d_in[2];
    const int*   vlens   = (const int*)  d_in[3];
    const float* Wq      = (const float*)d_in[4];
    const float* Wk      = (const float*)d_in[5];
    const float* Wv      = (const float*)d_in[6];
    float* out = (float*)d_out;

    float4* qdatA  = (float4*)d_ws;                  // 32768 float4 (512 KB)
    float4* qdatB  = qdatA + NB * 32 * NH;           // 32768 float4 (512 KB)
    float4* kTt    = qdatB + NB * 32 * NH;           // 262144 float4 (4 MB, tiled)
    float*  part_m = (float*)(kTt + NB * 64 * NK);   // 8192 floats
    float*  part_s = part_m + 8192;                  // 8192 floats
    float*  part_pv = part_s + 8192;                 // 2M floats (8 MB)

    proj_kernel   <<<dim3(640), dim3(256), 0, stream>>>(queries, keys, Wq, Wk, Wv,
                                                        qdatA, qdatB, kTt);
    attn_kernel   <<<dim3(2048), dim3(256), 0, stream>>>(qdatA, qdatB, kTt, values,
                                                         vlens, (const float4*)Wv,
                                                         part_m, part_s, part_pv);
    combine_kernel<<<dim3(512), dim3(256), 0, stream>>>(part_m, part_s, part_pv,
                                                        vlens, out);
}

// Round 8
// 125.133 us; speedup vs baseline: 1.5975x; 1.0079x over previous
//
#include <hip/hip_runtime.h>

#define NB 4
#define NQ 128
#define NK 1024
#define NH 256
#define NE 256
#define NV 256

#define TSCALE 2.8853900817779268f  // 2*log2(e)
#define LOG2E  1.4426950408889634f

static __device__ __forceinline__ float fexp2(float x){ return __builtin_amdgcn_exp2f(x); }
static __device__ __forceinline__ float frcp (float x){ return __builtin_amdgcn_rcpf(x); }
static __device__ __forceinline__ float tanh_of(float x){
    float e = fexp2(x * TSCALE);
    return fmaf(-2.0f, frcp(e + 1.0f), 1.0f);
}

// ---------------- proj: blocks [0,128): q-side (4 rows each) -> qdatA/qdatB packed
//                        blocks [128,640): k-side (8 rows each) -> kTt tiled
// kTt float4 index: ((b*16 + c)*64 + h4)*64 + kl   (c = k>>6, kl = k&63)
__global__ __launch_bounds__(256) void proj_kernel(
    const float* __restrict__ qin, const float* __restrict__ kin,
    const float* __restrict__ Wq, const float* __restrict__ Wk,
    const float* __restrict__ Wv,
    float4* __restrict__ qdatA, float4* __restrict__ qdatB,
    float4* __restrict__ kTt) {
    const int tid = threadIdx.x;
    const int bi  = blockIdx.x;
    __shared__ float tr[NH][9];
    if (bi < NB * 32) {
        const int row0 = bi * 4;
        const float* r0 = qin + row0 * NE;
        float a0 = 0.f, a1 = 0.f, a2 = 0.f, a3 = 0.f;
#pragma unroll 2
        for (int e = 0; e < NE; e += 4) {
            float4 q0 = *(const float4*)(r0 + e);
            float4 q1 = *(const float4*)(r0 + NE + e);
            float4 q2 = *(const float4*)(r0 + 2 * NE + e);
            float4 q3 = *(const float4*)(r0 + 3 * NE + e);
#pragma unroll
            for (int j = 0; j < 4; ++j) {
                float w = Wq[(e + j) * NH + tid];
                a0 = fmaf(((const float*)&q0)[j], w, a0);
                a1 = fmaf(((const float*)&q1)[j], w, a1);
                a2 = fmaf(((const float*)&q2)[j], w, a2);
                a3 = fmaf(((const float*)&q3)[j], w, a3);
            }
        }
        float wv = Wv[tid];
        float t0 = tanh_of(a0), t1 = tanh_of(a1), t2 = tanh_of(a2), t3 = tanh_of(a3);
        qdatA[bi * NH + tid] = make_float4(t0, wv * t0, t1, wv * t1);
        qdatB[bi * NH + tid] = make_float4(t2, wv * t2, t3, wv * t3);
    } else {
        const int kb = bi - NB * 32;
        const int b  = kb >> 7;
        const int k0 = (kb & 127) * 8;
        const int c   = k0 >> 6;
        const int kl0 = k0 & 63;
        const float* kr = kin + (b * NK + k0) * NE;
        float acc[8] = {0.f,0.f,0.f,0.f,0.f,0.f,0.f,0.f};
#pragma unroll 2
        for (int e = 0; e < NE; e += 4) {
            float4 kvv[8];
#pragma unroll
            for (int i = 0; i < 8; ++i) kvv[i] = *(const float4*)(kr + i * NE + e);
#pragma unroll
            for (int j = 0; j < 4; ++j) {
                float w = Wk[(e + j) * NH + tid];
#pragma unroll
                for (int i = 0; i < 8; ++i)
                    acc[i] = fmaf(((const float*)&kvv[i])[j], w, acc[i]);
            }
        }
#pragma unroll
        for (int i = 0; i < 8; ++i) tr[tid][i] = tanh_of(acc[i]);
        __syncthreads();
#pragma unroll
        for (int p = 0; p < 2; ++p) {
            int idx2 = p * 256 + tid;
            int hg = idx2 >> 3;
            int kk = idx2 & 7;
            float4 v = make_float4(tr[hg*4+0][kk], tr[hg*4+1][kk],
                                   tr[hg*4+2][kk], tr[hg*4+3][kk]);
            kTt[((b * 16 + c) * 64 + hg) * 64 + kl0 + kk] = v;
        }
    }
}

// one h4-step: 4 h-elements x 4 q-rows, ONE rcp via 4-way batched reciprocal
static __device__ __forceinline__ void step4(
    float4 kv4, const float4* __restrict__ qA, const float4* __restrict__ qB,
    const float4* __restrict__ Wv4, int h4,
    float& acc0, float& acc1, float& acc2, float& acc3) {
    float4 wv4 = Wv4[h4];                    // wave-uniform -> scalar cache
#pragma unroll
    for (int j = 0; j < 4; ++j) {
        float kv  = (j==0)?kv4.x:(j==1)?kv4.y:(j==2)?kv4.z:kv4.w;
        float wvj = (j==0)?wv4.x:(j==1)?wv4.y:(j==2)?wv4.z:wv4.w;
        float wvb = wvj * kv;
        float4 qa = qA[h4 * 4 + j];          // wave-uniform -> scalar cache
        float4 qb = qB[h4 * 4 + j];
        float p0 = fmaf(qa.x, kv, 1.0f), nu0 = qa.y + wvb;
        float p1 = fmaf(qa.z, kv, 1.0f), nu1 = qa.w + wvb;
        float p2 = fmaf(qb.x, kv, 1.0f), nu2 = qb.y + wvb;
        float p3 = fmaf(qb.z, kv, 1.0f), nu3 = qb.w + wvb;
        float ab = p0 * p1, cd = p2 * p3;
        float r  = frcp(ab * cd);
        float rab = r * cd, rcd = r * ab;
        acc0 = fmaf(nu0, rab * p1, acc0);
        acc1 = fmaf(nu1, rab * p0, acc1);
        acc2 = fmaf(nu2, rcd * p3, acc2);
        acc3 = fmaf(nu3, rcd * p2, acc3);
    }
}

// ---------------- fused attention with XCD-aware swizzle:
// blockIdx = jj*8 + xcd; gslot = (jj>>5)*8 + xcd; qq = jj&31.
// All 32 qq-blocks of one (b,chunk) group share blockIdx%8 -> same XCD ->
// kTt/V tiles fetched from L3 once, then served from that XCD's L2.
__global__ __launch_bounds__(256) void attn_kernel(
    const float4* __restrict__ qdatA, const float4* __restrict__ qdatB,
    const float4* __restrict__ kTt, const float* __restrict__ V,
    const int* __restrict__ vlen, const float4* __restrict__ Wv4,
    float* __restrict__ part_m, float* __restrict__ part_s,
    float* __restrict__ part_pv) {
    const int tid = threadIdx.x, lane = tid & 63, wvid = tid >> 6;
    const int n0 = (vlen[0] + 63) >> 6, n1 = (vlen[1] + 63) >> 6;
    const int n2 = (vlen[2] + 63) >> 6, n3 = (vlen[3] + 63) >> 6;
    const int G  = n0 + n1 + n2 + n3;       // valid (b,chunk) groups (<=64)
    const int bi = blockIdx.x;
    const int xcd = bi & 7;
    const int jj  = bi >> 3;
    const int qq  = jj & 31;
    const int gs  = ((jj >> 5) << 3) + xcd; // group slot; gs%8 == xcd
    if (gs >= G) return;
    int b, chunk;
    if      (gs < n0)           { b = 0; chunk = gs; }
    else if (gs < n0 + n1)      { b = 1; chunk = gs - n0; }
    else if (gs < n0 + n1 + n2) { b = 2; chunk = gs - n0 - n1; }
    else                        { b = 3; chunk = gs - n0 - n1 - n2; }
    const int vl    = vlen[b];
    const int k0    = chunk * 64;
    const int k     = k0 + lane;
    const int pidx  = (b * 32 + qq) * 16 + chunk;
    float* pm  = part_m + pidx * 4;
    float* ps  = part_s + pidx * 4;
    float* ppv = part_pv + pidx * (4 * NV);

    __shared__ float red17[4][64 * 17];   // phase A: h-partials; phase B: pv-partials
    __shared__ float pwS[4][64];          // softmax weights, [q-row][k-lane]

    const float4* qA = qdatA + (b * 32 + qq) * NH;   // wave-uniform
    const float4* qB = qdatB + (b * 32 + qq) * NH;

    // phase A: scores — wave wvid reads a contiguous 16KB window of the tile
    const float4* kp = kTt + ((b * 16 + chunk) * 64 + wvid * 16) * 64 + lane;
    float acc0 = 0.f, acc1 = 0.f, acc2 = 0.f, acc3 = 0.f;
#pragma unroll 4
    for (int i = 0; i < 16; ++i) {
        float4 kv4 = kp[i * 64];          // sequential 1KB wave-loads, L2-local
        step4(kv4, qA, qB, Wv4, wvid * 16 + i, acc0, acc1, acc2, acc3);
    }
    {
        float* hp = &red17[wvid][lane * 17];
        hp[0] = acc0; hp[1] = acc1; hp[2] = acc2; hp[3] = acc3;
    }
    __syncthreads();
    // cross-wave h-reduce; wave = q-row, lane = k-lane
    {
        const int row = wvid;
        float s = red17[0][lane * 17 + row] + red17[1][lane * 17 + row]
                + red17[2][lane * 17 + row] + red17[3][lane * 17 + row];
        s = (k < vl) ? s : -1e30f;
        float m = s;
#pragma unroll
        for (int d = 32; d >= 1; d >>= 1) m = fmaxf(m, __shfl_xor(m, d, 64));
        float p = fexp2((s - m) * LOG2E);     // masked -> exactly 0
        float u = p;
#pragma unroll
        for (int d = 32; d >= 1; d >>= 1) u += __shfl_xor(u, d, 64);
        if (lane == 0) { pm[row] = m; ps[row] = u; }
        pwS[row][lane] = p;
    }
    __syncthreads();
    // phase B: PV — wave wvid covers kk in [wvid*16, wvid*16+16), all 4 q-rows
    {
        const float* Vb = V + (b * NK + k0) * NV;
        const int v4 = lane * 4;
        float4 o0 = {0,0,0,0}, o1 = {0,0,0,0}, o2 = {0,0,0,0}, o3 = {0,0,0,0};
#pragma unroll 4
        for (int kk = 0; kk < 16; ++kk) {
            const int kkk = wvid * 16 + kk;
            float p0 = pwS[0][kkk], p1 = pwS[1][kkk];   // uniform -> broadcast
            float p2 = pwS[2][kkk], p3 = pwS[3][kkk];
            float4 vv = *(const float4*)&Vb[kkk * NV + v4];
            o0.x = fmaf(p0, vv.x, o0.x); o0.y = fmaf(p0, vv.y, o0.y);
            o0.z = fmaf(p0, vv.z, o0.z); o0.w = fmaf(p0, vv.w, o0.w);
            o1.x = fmaf(p1, vv.x, o1.x); o1.y = fmaf(p1, vv.y, o1.y);
            o1.z = fmaf(p1, vv.z, o1.z); o1.w = fmaf(p1, vv.w, o1.w);
            o2.x = fmaf(p2, vv.x, o2.x); o2.y = fmaf(p2, vv.y, o2.y);
            o2.z = fmaf(p2, vv.z, o2.z); o2.w = fmaf(p2, vv.w, o2.w);
            o3.x = fmaf(p3, vv.x, o3.x); o3.y = fmaf(p3, vv.y, o3.y);
            o3.z = fmaf(p3, vv.z, o3.z); o3.w = fmaf(p3, vv.w, o3.w);
        }
        float* pd = &red17[wvid][lane * 17];
        *(float4*)(pd + 0)  = o0;
        *(float4*)(pd + 4)  = o1;
        *(float4*)(pd + 8)  = o2;
        *(float4*)(pd + 12) = o3;
    }
    __syncthreads();
    {
        const int row = tid >> 6, vg = tid & 63;
        float4 r = {0,0,0,0};
#pragma unroll
        for (int ww = 0; ww < 4; ++ww) {
            float4 t = *(const float4*)&red17[ww][vg * 17 + row * 4];
            r.x += t.x; r.y += t.y; r.z += t.z; r.w += t.w;
        }
        *(float4*)&ppv[row * NV + vg * 4] = r;
    }
}

// ---------------- combine: 512 blocks — one (b*32+qq, q-row) each
__global__ __launch_bounds__(256) void combine_kernel(
    const float* __restrict__ part_m, const float* __restrict__ part_s,
    const float* __restrict__ part_pv, const int* __restrict__ vlen,
    float* __restrict__ out) {
    const int tid = threadIdx.x;
    const int idx = blockIdx.x;     // 0..511
    const int bi  = idx >> 2;       // b*32+qq
    const int i   = idx & 3;        // q-row within group
    const int b   = bi >> 5;
    const int nb  = (vlen[b] + 63) >> 6;    // valid chunks (1..16)
    const int base = bi * 16;
    float M = -1e30f;
    for (int q = 0; q < nb; ++q)
        M = fmaxf(M, part_m[(base + q) * 4 + i]);
    float S = 0.f, o = 0.f;
    for (int q = 0; q < nb; ++q) {
        float wq = fexp2((part_m[(base + q) * 4 + i] - M) * LOG2E);
        S = fmaf(part_s[(base + q) * 4 + i], wq, S);
        o = fmaf(part_pv[((base + q) * 4 + i) * NV + tid], wq, o);
    }
    out[(bi * 4 + i) * NV + tid] = o * frcp(S);
}

extern "C" void kernel_launch(void* const* d_in, const int* in_sizes, int n_in,
                              void* d_out, int out_size, void* d_ws, size_t ws_size,
                              hipStream_t stream) {
    const float* queries = (const float*)d_in[0];
    const float* keys    = (const float*)d_in[1];
    const float* values  = (const float*)d_in[2];
    const int*   vlens   = (const int*)  d_in[3];
    const float* Wq      = (const float*)d_in[4];
    const float* Wk      = (const float*)d_in[5];
    const float* Wv      = (const float*)d_in[6];
    float* out = (float*)d_out;

    float4* qdatA  = (float4*)d_ws;                  // 32768 float4 (512 KB)
    float4* qdatB  = qdatA + NB * 32 * NH;           // 32768 float4 (512 KB)
    float4* kTt    = qdatB + NB * 32 * NH;           // 262144 float4 (4 MB, tiled)
    float*  part_m = (float*)(kTt + NB * 64 * NK);   // 8192 floats
    float*  part_s = part_m + 8192;                  // 8192 floats
    float*  part_pv = part_s + 8192;                 // 2M floats (8 MB)

    proj_kernel   <<<dim3(640), dim3(256), 0, stream>>>(queries, keys, Wq, Wk, Wv,
                                                        qdatA, qdatB, kTt);
    attn_kernel   <<<dim3(2048), dim3(256), 0, stream>>>(qdatA, qdatB, kTt, values,
                                                         vlens, (const float4*)Wv,
                                                         part_m, part_s, part_pv);
    combine_kernel<<<dim3(512), dim3(256), 0, stream>>>(part_m, part_s, part_pv,
                                                        vlens, out);
}